// Round 3
// baseline (191.823 us; speedup 1.0000x reference)
//
#include <hip/hip_runtime.h>
#include <cfloat>
#include <cstdint>

// Problem constants (B=4, N=2048, C=64, O=64, K=20)
#define M_TOTAL 8192
#define KNN 20
#define PPART 8                  // candidate partitions
#define CPB (M_TOTAL / PPART)    // 1024 candidates per K1b block
#define QT 128                   // queries per K1b block (big blocks: amortize setup)
#define QT1A 32                  // queries per K1a block
#define SAMPLE 1024              // tau sample = candidates [0, 1024)
#define CAP 64                   // collect capacity per (query,partition); E~22, 9 sigma
#define SLOTS (PPART * CAP)      // 512
#define QT2 32                   // queries per K2ab block
#define NSLICE 8                 // slices per K2ab block (1 partition each)
#define GCAP 40                  // guard-collect cap in k2ab

typedef __attribute__((ext_vector_type(8))) short bf16x8;  // 8 bf16 (4 VGPRs)
typedef __attribute__((ext_vector_type(4))) float f32x4;

__device__ __forceinline__ unsigned short bf16rne(float x) {
  unsigned u = __float_as_uint(x);
  return (unsigned short)((u + 0x7FFFu + ((u >> 16) & 1u)) >> 16);
}

// ---------------------------------------------------------------------------
// K0: per-point precompute. sq, bf16 pos (hi only; k2ab re-ranks exact fp32),
// factored layer-1 (a, g). Blocks 0-1 also emit the W2 B-frag swizzle.
// ---------------------------------------------------------------------------
__global__ __launch_bounds__(256) void k0_pre(
    const float* __restrict__ pos, const float* __restrict__ feat,
    const float* __restrict__ W1, const float* __restrict__ b1,
    const float* __restrict__ W2,
    float* __restrict__ sq, float* __restrict__ a_out, float* __restrict__ g_out,
    unsigned short* __restrict__ poshi, unsigned short* __restrict__ w2sw) {
  __shared__ float fLds[4][64];
  const int lane = threadIdx.x & 63;
  const int rl = threadIdx.x >> 6;
  const int r = blockIdx.x * 4 + rl;

  float p = pos[r * 64 + lane];
  float f = feat[r * 64 + lane];
  fLds[rl][lane] = f;  // wave-private row; wave lockstep

  poshi[r * 64 + lane] = bf16rne(p);

  float s = p * p;
#pragma unroll
  for (int off = 1; off < 64; off <<= 1) s += __shfl_xor(s, off, 64);
  if (lane == 0) sq[r] = s;

  float acc_a = b1[lane];
  float acc_g = 0.f;
  const float4* f4 = reinterpret_cast<const float4*>(fLds[rl]);
#pragma unroll
  for (int i = 0; i < 16; ++i) {
    float4 fv = f4[i];
    float fd[4] = {fv.x, fv.y, fv.z, fv.w};
#pragma unroll
    for (int j = 0; j < 4; ++j) {
      int d = 4 * i + j;
      float wt = W1[d * 64 + lane];
      float wb = W1[(64 + d) * 64 + lane];
      acc_a = fmaf(fd[j], wt - wb, acc_a);
      acc_g = fmaf(fd[j], wb, acc_g);
    }
  }
  a_out[r * 64 + lane] = acc_a;
  g_out[r * 64 + lane] = acc_g;

  if (blockIdx.x < 2) {  // fused W2 swizzle (frag f = seg*4 + t)
    const int u = blockIdx.x * 256 + threadIdx.x;  // [0, 512)
    const int fr = u >> 6, ul = u & 63;
    const int seg = fr >> 2, t = fr & 3;
    const int uq = ul >> 4, uc = ul & 15;
#pragma unroll
    for (int j = 0; j < 8; ++j) {
      int d = seg * 32 + uq * 8 + j;
      w2sw[u * 8 + j] = bf16rne(W2[d * 64 + t * 16 + uc]);
    }
  }
}

// ---------------------------------------------------------------------------
// K1a: tau_q >= sample-20th d-hat (overestimate widens superset: safe).
// 256 blocks; top-8 per 128-cand stream; tau = 20th of 64 kept, +0.5 margin
// for hi-only d-hat error. A[m=lane&15][k=quad*8+j]; D: col=lane&15,
// row=quad*4+reg (m89-verified).
// ---------------------------------------------------------------------------
__global__ __launch_bounds__(256) void k1a_tau(
    const unsigned short* __restrict__ poshi,
    const float* __restrict__ sq, float* __restrict__ tau_g) {
  __shared__ float vw[4][16][36];        // wave-private transpose, 9 KiB
  __shared__ float sqcLds[SAMPLE];       // 4 KiB
  __shared__ float topLds[8][8][33];     // [stream][k][q], 8.25 KiB
  const int lane = threadIdx.x & 63;
  const int w = threadIdx.x >> 6;
  const int qbase = blockIdx.x * QT1A;
  const int col = lane & 15;
  const int quad = lane >> 4;
  const int dimOff = quad * 8;
  const int qq = lane & 31;     // query owned in cascade phase
  const int h = lane >> 5;      // candidate half owned

  for (int i = threadIdx.x; i < SAMPLE; i += 256) sqcLds[i] = sq[i];

  bf16x8 Ahi[2][2];
#pragma unroll
  for (int s = 0; s < 2; ++s) {
    int row = qbase + s * 16 + col;
    Ahi[s][0] = *(const bf16x8*)(poshi + (size_t)row * 64 + dimOff);
    Ahi[s][1] = *(const bf16x8*)(poshi + (size_t)row * 64 + dimOff + 32);
  }
  __syncthreads();  // sqcLds ready

  const f32x4 zf = {0.f, 0.f, 0.f, 0.f};
  float bd[8];
#pragma unroll
  for (int k = 0; k < 8; ++k) bd[k] = FLT_MAX;

  bf16x8 Bh0 = *(const bf16x8*)(poshi + (size_t)(w * 16 + col) * 64 + dimOff);
  bf16x8 Bh1 = *(const bf16x8*)(poshi + (size_t)(w * 16 + col) * 64 + dimOff + 32);
  for (int c0 = 0; c0 < SAMPLE; c0 += 64) {
    const int nc0 = (c0 + 64 < SAMPLE) ? c0 + 64 : c0;
    bf16x8 Nh0 = *(const bf16x8*)(poshi + (size_t)(nc0 + w * 16 + col) * 64 + dimOff);
    bf16x8 Nh1 = *(const bf16x8*)(poshi + (size_t)(nc0 + w * 16 + col) * 64 + dimOff + 32);

    f32x4 acc[2] = {zf, zf};
#pragma unroll
    for (int s = 0; s < 2; ++s) {
      acc[s] = __builtin_amdgcn_mfma_f32_16x16x32_bf16(Ahi[s][0], Bh0, acc[s], 0, 0, 0);
      acc[s] = __builtin_amdgcn_mfma_f32_16x16x32_bf16(Ahi[s][1], Bh1, acc[s], 0, 0, 0);
    }
    const float sqcv = sqcLds[c0 + w * 16 + col] + 256.0f;
#pragma unroll
    for (int s = 0; s < 2; ++s) {
      float4 v4;
      v4.x = fmaf(-2.f, acc[s][0], sqcv);
      v4.y = fmaf(-2.f, acc[s][1], sqcv);
      v4.z = fmaf(-2.f, acc[s][2], sqcv);
      v4.w = fmaf(-2.f, acc[s][3], sqcv);
      *reinterpret_cast<float4*>(&vw[w][col][s * 16 + quad * 4]) = v4;
    }
    __builtin_amdgcn_wave_barrier();  // wave-private region, lockstep
#pragma unroll
    for (int i = 0; i < 8; ++i) {
      float cd = vw[w][h * 8 + i][qq];
#pragma unroll
      for (int k = 0; k < 8; ++k) {  // branch-free sorted insert (top-8)
        float lo = fminf(cd, bd[k]);
        cd = fmaxf(cd, bd[k]);
        bd[k] = lo;
      }
    }
    __builtin_amdgcn_wave_barrier();
    Bh0 = Nh0; Bh1 = Nh1;
  }

#pragma unroll
  for (int k = 0; k < 8; ++k) topLds[w * 2 + h][k][qq] = bd[k];
  __syncthreads();

  if (threadIdx.x < QT1A) {
    const int l = threadIdx.x;
    int ix[8] = {0, 0, 0, 0, 0, 0, 0, 0};
    float tau = FLT_MAX;
    for (int k = 0; k < KNN; ++k) {
      float best = FLT_MAX;
      int bs = 0;
#pragma unroll
      for (int st = 0; st < 8; ++st) {
        float v = (ix[st] < 8) ? topLds[st][ix[st]][l] : FLT_MAX;
        if (v < best) { best = v; bs = st; }
      }
      ix[bs]++;
      tau = best;
    }
    tau_g[qbase + l] = tau + 0.5f;  // margin covers hi-only d-hat error
  }
}

// ---------------------------------------------------------------------------
// K1b v9: 512-thread blocks (8 waves). Round-1 profile: 52 us with MfmaUtil
// 5.9%, VALUBusy 25%, Occupancy 19% -- latency-bound at 2 waves/SIMD (grid
// 512 x 4 waves = 8 waves/CU). Fix: widen to 8 waves/block so residency is
// 2 blocks x 8 waves = 16 waves/CU = 4 waves/SIMD (VGPR 84 <= 128 allows).
// Stripe covers 128 candidates/iter (wave w owns w*16+col), 8 iterations.
// Per-wave structure, list/cnt layout, and collect semantics unchanged.
// ---------------------------------------------------------------------------
__global__ __launch_bounds__(512, 4) void k1b_collect(
    const unsigned short* __restrict__ poshi,
    const float* __restrict__ sq, const float* __restrict__ tau_g,
    unsigned* __restrict__ list, unsigned* __restrict__ cnt_ws) {
  __shared__ float sqcLds[CPB];      // 4 KiB
  __shared__ float tauLds[QT];
  __shared__ unsigned cntLds[QT];

  const int lane = threadIdx.x & 63;
  const int w = threadIdx.x >> 6;    // 0..7
  const int qbase = blockIdx.x * QT;
  const int cbase = blockIdx.y * CPB;
  const int col = lane & 15;
  const int quad = lane >> 4;
  const int dimOff = quad * 8;

  for (int i = threadIdx.x; i < CPB; i += 512) sqcLds[i] = sq[cbase + i];
  if (threadIdx.x < QT) {
    tauLds[threadIdx.x] = tau_g[qbase + threadIdx.x];
    cntLds[threadIdx.x] = 0;
  }

  // A-fragments: 8 groups of 16 queries (loaded once, reused for 8 stripes)
  bf16x8 Ahi[8][2];
#pragma unroll
  for (int s = 0; s < 8; ++s) {
    int row = qbase + s * 16 + col;
    Ahi[s][0] = *(const bf16x8*)(poshi + (size_t)row * 64 + dimOff);
    Ahi[s][1] = *(const bf16x8*)(poshi + (size_t)row * 64 + dimOff + 32);
  }
  __syncthreads();

  float tau_l[8][4];
#pragma unroll
  for (int s = 0; s < 8; ++s)
#pragma unroll
    for (int r = 0; r < 4; ++r) tau_l[s][r] = tauLds[s * 16 + quad * 4 + r];

  const f32x4 zf = {0.f, 0.f, 0.f, 0.f};
  bf16x8 Bh0 = *(const bf16x8*)(poshi + (size_t)(cbase + w * 16 + col) * 64 + dimOff);
  bf16x8 Bh1 = *(const bf16x8*)(poshi + (size_t)(cbase + w * 16 + col) * 64 + dimOff + 32);
  for (int c0 = 0; c0 < CPB; c0 += 128) {
    const int nc0 = (c0 + 128 < CPB) ? c0 + 128 : c0;
    bf16x8 Nh0 = *(const bf16x8*)(poshi + (size_t)(cbase + nc0 + w * 16 + col) * 64 + dimOff);
    bf16x8 Nh1 = *(const bf16x8*)(poshi + (size_t)(cbase + nc0 + w * 16 + col) * 64 + dimOff + 32);

    f32x4 acc[8] = {zf, zf, zf, zf, zf, zf, zf, zf};
#pragma unroll
    for (int s = 0; s < 8; ++s) {
      acc[s] = __builtin_amdgcn_mfma_f32_16x16x32_bf16(Ahi[s][0], Bh0, acc[s], 0, 0, 0);
      acc[s] = __builtin_amdgcn_mfma_f32_16x16x32_bf16(Ahi[s][1], Bh1, acc[s], 0, 0, 0);
    }
    const int candRow = cbase + c0 + w * 16 + col;
    const float sqcv = sqcLds[c0 + w * 16 + col] + 256.0f;
#pragma unroll
    for (int s = 0; s < 8; ++s) {
#pragma unroll
      for (int r = 0; r < 4; ++r) {
        float val = fmaf(-2.f, acc[s][r], sqcv);
        const int qrow = s * 16 + quad * 4 + r;  // D row = quad*4+reg
        if (val <= tau_l[s][r]) {  // ~0.3% of lanes
          unsigned slot = atomicAdd(&cntLds[qrow], 1u);
          if (slot < CAP)
            list[(size_t)(blockIdx.y * CAP + slot) * M_TOTAL + qbase + qrow] =
                (__float_as_uint(val) & 0xFFFFE000u) | (unsigned)candRow;
        }
      }
    }
    Bh0 = Nh0; Bh1 = Nh1;
  }
  __syncthreads();
  if (threadIdx.x < QT) {
    unsigned c = cntLds[threadIdx.x];
    cnt_ws[blockIdx.y * M_TOTAL + qbase + threadIdx.x] = c > CAP ? CAP : c;
  }
}

// ---------------------------------------------------------------------------
// K2ab: fused selection + MLP. 32 queries x 8 slices (1 partition each).
// Ph1: per-slice top-8 (coalesced; kept-20th >= true-20th, safe T).
// Ph2: 8-way merge -> 20th of kept -> guard T (+3 quanta for hi-only error).
// Ph3: rescan, collect quant <= T (~22/query).
// Ph4: 8 thr/query exact fp32 d2, sorted-5 each; merge top-20 -> nbrLds.
// Ph5 (fused former k2b): MLP via MFMA, 4 waves x 8 rounds over the block's
// 32 queries; nbr never leaves LDS; coalesced out store.
// ---------------------------------------------------------------------------
__global__ __launch_bounds__(256) void k2ab(
    const float* __restrict__ pos, const float* __restrict__ sq,
    const unsigned* __restrict__ list, const unsigned* __restrict__ cnt_ws,
    const float* __restrict__ a_in, const float* __restrict__ g_in,
    const unsigned short* __restrict__ w2sw, const float* __restrict__ b2,
    float* __restrict__ out) {
  __shared__ unsigned topLds[NSLICE][QT2][9];           // 9.2 KiB (pad 9)
  __shared__ unsigned TLds[QT2];
  __shared__ unsigned ccnt[QT2];
  __shared__ unsigned candLds[QT2][GCAP];               // 5.1 KiB
  __shared__ unsigned long long rrLds[NSLICE][QT2][6];  // 12.3 KiB (pad 6)
  __shared__ int nbrLds[QT2][KNN];                      // 2.5 KiB

  const int l = threadIdx.x & 31;   // query lane
  const int s = threadIdx.x >> 5;   // slice: partition s
  const int q = blockIdx.x * QT2 + l;

  // ---- phase 1: per-slice top-8 over collected keys (chunked loads) ----
  unsigned bd[8];
#pragma unroll
  for (int k = 0; k < 8; ++k) bd[k] = 0xFFFFFFFFu;
  {
    const unsigned c = cnt_ws[s * M_TOTAL + q];
    const unsigned* base = list + (size_t)(s * CAP) * M_TOTAL + q;
    for (unsigned sl0 = 0; sl0 < c; sl0 += 8) {
      unsigned kk[8];
#pragma unroll
      for (int j = 0; j < 8; ++j) {
        unsigned slj = sl0 + j;
        kk[j] = base[(size_t)(slj < c ? slj : 0) * M_TOTAL];  // 8 loads in flight
      }
#pragma unroll
      for (int j = 0; j < 8; ++j) {
        unsigned cd = (sl0 + j < c) ? kk[j] : 0xFFFFFFFFu;
#pragma unroll
        for (int k = 0; k < 8; ++k) {
          unsigned lo = cd < bd[k] ? cd : bd[k];
          cd = cd < bd[k] ? bd[k] : cd;
          bd[k] = lo;
        }
      }
    }
  }
#pragma unroll
  for (int k = 0; k < 8; ++k) topLds[s][l][k] = bd[k];
  __syncthreads();

  // ---- phase 2: 8-way merge -> 20th of kept -> guard T ----
  if (threadIdx.x < QT2) {
    int ix[8] = {0, 0, 0, 0, 0, 0, 0, 0};
    unsigned m = 0;
    for (int k = 0; k < KNN; ++k) {
      unsigned best = 0xFFFFFFFFu;
      int bs = 0;
#pragma unroll
      for (int st = 0; st < 8; ++st) {
        unsigned v = (ix[st] < 8) ? topLds[st][l][ix[st]] : 0xFFFFFFFFu;
        if (v < best) { best = v; bs = st; }
      }
      ix[bs]++;
      m = best;
    }
    TLds[l] = (m >> 13) + 3;
    ccnt[l] = 0;
  }
  __syncthreads();

  // ---- phase 3: rescan, collect guard set (chunked loads) ----
  const unsigned T = TLds[l];
  {
    const unsigned c = cnt_ws[s * M_TOTAL + q];
    const unsigned* base = list + (size_t)(s * CAP) * M_TOTAL + q;
    for (unsigned sl0 = 0; sl0 < c; sl0 += 8) {
      unsigned kk[8];
#pragma unroll
      for (int j = 0; j < 8; ++j) {
        unsigned slj = sl0 + j;
        kk[j] = base[(size_t)(slj < c ? slj : 0) * M_TOTAL];
      }
#pragma unroll
      for (int j = 0; j < 8; ++j) {
        if (sl0 + j < c && (kk[j] >> 13) <= T) {
          unsigned pos_ = atomicAdd(&ccnt[l], 1u);
          if (pos_ < GCAP) candLds[l][pos_] = kk[j] & 0x1FFFu;
        }
      }
    }
  }
  __syncthreads();

  // ---- phase 4: exact fp32 d2 re-rank of the guard set ----
  const int cc = min(ccnt[l], (unsigned)GCAP);
  const float sqq = sq[q];
  const float4* qp4 = reinterpret_cast<const float4*>(pos + (size_t)q * 64);
  unsigned long long kb[5];
#pragma unroll
  for (int j = 0; j < 5; ++j) kb[j] = ~0ull;
  for (int j = s; j < cc; j += NSLICE) {
    const unsigned idx = candLds[l][j];
    const float4* cp4 = reinterpret_cast<const float4*>(pos + (size_t)idx * 64);
    float d0 = 0.f, d1 = 0.f, d2 = 0.f, d3 = 0.f;
#pragma unroll
    for (int t = 0; t < 16; ++t) {
      float4 cv = cp4[t];
      float4 qv = qp4[t];  // L1/L2-hot
      d0 = fmaf(cv.x, qv.x, d0);
      d1 = fmaf(cv.y, qv.y, d1);
      d2 = fmaf(cv.z, qv.z, d2);
      d3 = fmaf(cv.w, qv.w, d3);
    }
    float dot = (d0 + d1) + (d2 + d3);
    float dd = fmaxf(fmaf(-2.f, dot, sqq + sq[idx]), 0.f);
    unsigned long long cd = ((unsigned long long)__float_as_uint(dd) << 32) | idx;
#pragma unroll
    for (int k = 0; k < 5; ++k) {  // sorted-5 insert (tie -> smaller idx)
      unsigned long long lo = cd < kb[k] ? cd : kb[k];
      cd = cd < kb[k] ? kb[k] : cd;
      kb[k] = lo;
    }
  }
#pragma unroll
  for (int j = 0; j < 5; ++j) rrLds[s][l][j] = kb[j];
  __syncthreads();

  if (threadIdx.x < QT2) {
    int ix[8] = {0, 0, 0, 0, 0, 0, 0, 0};
    for (int k = 0; k < KNN; ++k) {
      unsigned long long best = ~0ull;
      int bs = 0;
#pragma unroll
      for (int st = 0; st < 8; ++st) {
        unsigned long long v = (ix[st] < 5) ? rrLds[st][l][ix[st]] : ~0ull;
        if (v < best) { best = v; bs = st; }
      }
      ix[bs]++;
      nbrLds[l][k] = (int)(unsigned)(best & 0xFFFFFFFFu);
    }
  }
  __syncthreads();

  // ---- phase 5 (fused k2b): MLP + max-agg via MFMA, 4 waves x 8 rounds ----
  const int lane = threadIdx.x & 63;
  const int wv = threadIdx.x >> 6;
  const int col = lane & 15;
  const int quad = lane >> 4;

  bf16x8 Bf[8];
#pragma unroll
  for (int f = 0; f < 8; ++f)
    Bf[f] = *(const bf16x8*)(w2sw + ((size_t)f * 64 + lane) * 8);
  const float bias = b2[lane];

  for (int t = 0; t < 8; ++t) {
    const int li = t * 4 + wv;                 // local query 0..31
    const int q2 = blockIdx.x * QT2 + li;
    const int n0 = nbrLds[li][col];
    const int n1 = nbrLds[li][(16 + col) % KNN];

    const f32x4 zf = {0.f, 0.f, 0.f, 0.f};
    f32x4 acc0[4] = {zf, zf, zf, zf};
    f32x4 acc1[4] = {zf, zf, zf, zf};
#pragma unroll
    for (int seg = 0; seg < 2; ++seg) {
      const int dOff = seg * 32 + quad * 8;
      const float4* ap = reinterpret_cast<const float4*>(a_in + (size_t)q2 * 64 + dOff);
      const float4* g0p = reinterpret_cast<const float4*>(g_in + (size_t)n0 * 64 + dOff);
      const float4* g1p = reinterpret_cast<const float4*>(g_in + (size_t)n1 * 64 + dOff);
      float4 aa0 = ap[0], aa1 = ap[1];
      float4 gg0 = g0p[0], gg1 = g0p[1];
      float4 hh0 = g1p[0], hh1 = g1p[1];
      float av[8] = {aa0.x, aa0.y, aa0.z, aa0.w, aa1.x, aa1.y, aa1.z, aa1.w};
      float g0v[8] = {gg0.x, gg0.y, gg0.z, gg0.w, gg1.x, gg1.y, gg1.z, gg1.w};
      float g1v[8] = {hh0.x, hh0.y, hh0.z, hh0.w, hh1.x, hh1.y, hh1.z, hh1.w};
      bf16x8 A0, A1;
#pragma unroll
      for (int j = 0; j < 8; ++j) {
        A0[j] = (short)bf16rne(fmaxf(av[j] + g0v[j], 0.f));
        A1[j] = (short)bf16rne(fmaxf(av[j] + g1v[j], 0.f));
      }
#pragma unroll
      for (int tt = 0; tt < 4; ++tt) {
        acc0[tt] = __builtin_amdgcn_mfma_f32_16x16x32_bf16(A0, Bf[seg * 4 + tt], acc0[tt], 0, 0, 0);
        acc1[tt] = __builtin_amdgcn_mfma_f32_16x16x32_bf16(A1, Bf[seg * 4 + tt], acc1[tt], 0, 0, 0);
      }
    }
    float res = 0.f;
#pragma unroll
    for (int tt = 0; tt < 4; ++tt) {
      float m = fmaxf(fmaxf(fmaxf(acc0[tt][0], acc1[tt][0]), fmaxf(acc0[tt][1], acc1[tt][1])),
                      fmaxf(fmaxf(acc0[tt][2], acc1[tt][2]), fmaxf(acc0[tt][3], acc1[tt][3])));
      m = fmaxf(m, __shfl_xor(m, 16, 64));
      m = fmaxf(m, __shfl_xor(m, 32, 64));
      res = (quad == tt) ? m : res;  // o = tt*16+col == lane iff quad==tt
    }
    out[(size_t)q2 * 64 + lane] = res + bias;
  }
}

// ---------------------------------------------------------------------------
extern "C" void kernel_launch(void* const* d_in, const int* in_sizes, int n_in,
                              void* d_out, int out_size, void* d_ws, size_t ws_size,
                              hipStream_t stream) {
  const float* pos = (const float*)d_in[0];
  const float* feat = (const float*)d_in[1];
  const float* W1 = (const float*)d_in[2];
  const float* b1 = (const float*)d_in[3];
  const float* W2 = (const float*)d_in[4];
  const float* b2 = (const float*)d_in[5];
  float* out = (float*)d_out;

  // ws layout (bytes), total ~23.3 MiB:
  //   sq    @ 0         32 KiB
  //   a     @ 32768     2 MiB
  //   g     @ 2129920   2 MiB
  //   poshi @ 4227072   1 MiB
  //   w2sw  @ 6324224   8 KiB
  //   list  @ 6332416   16 MiB  (512 slots x 8192 queries, transposed u32 keys)
  //   cnt   @ 23109632  256 KiB (8 x 8192, transposed)
  //   tau   @ 23633920  32 KiB
  char* ws = (char*)d_ws;
  float* sq = (float*)ws;
  float* a = (float*)(ws + 32768);
  float* g = (float*)(ws + 2129920);
  unsigned short* poshi = (unsigned short*)(ws + 4227072);
  unsigned short* w2sw = (unsigned short*)(ws + 6324224);
  unsigned* list = (unsigned*)(ws + 6332416);
  unsigned* cnt_ws = (unsigned*)(ws + 23109632);
  float* tau_g = (float*)(ws + 23633920);

  k0_pre<<<M_TOTAL / 4, 256, 0, stream>>>(pos, feat, W1, b1, W2, sq, a, g, poshi, w2sw);
  k1a_tau<<<M_TOTAL / QT1A, 256, 0, stream>>>(poshi, sq, tau_g);
  k1b_collect<<<dim3(M_TOTAL / QT, PPART), 512, 0, stream>>>(poshi, sq, tau_g, list, cnt_ws);
  k2ab<<<M_TOTAL / QT2, 256, 0, stream>>>(pos, sq, list, cnt_ws, a, g, w2sw, b2, out);
}

// Round 4
// 170.681 us; speedup vs baseline: 1.1239x; 1.1239x over previous
//
#include <hip/hip_runtime.h>
#include <cfloat>
#include <cstdint>

// Problem constants (B=4, N=2048, C=64, O=64, K=20)
#define M_TOTAL 8192
#define KNN 20
#define PPART 8                  // candidate partitions
#define CPB (M_TOTAL / PPART)    // 1024 candidates per K1b block
#define QT1B 64                  // queries per K1b block (v10: halved for 2x grid TLP)
#define QT1A 32                  // queries per K1a block
#define SAMPLE 1024              // tau sample = candidates [0, 1024)
#define CAP 64                   // collect capacity per (query,partition); E~22, 9 sigma
#define SLOTS (PPART * CAP)      // 512
#define QT2 32                   // queries per K2ab block
#define NSLICE 8                 // slices per K2ab block (1 partition each)
#define GCAP 40                  // guard-collect cap in k2ab

typedef __attribute__((ext_vector_type(8))) short bf16x8;  // 8 bf16 (4 VGPRs)
typedef __attribute__((ext_vector_type(4))) float f32x4;

__device__ __forceinline__ unsigned short bf16rne(float x) {
  unsigned u = __float_as_uint(x);
  return (unsigned short)((u + 0x7FFFu + ((u >> 16) & 1u)) >> 16);
}

// ---------------------------------------------------------------------------
// K0: per-point precompute. sq, bf16 pos (hi only; k2ab re-ranks exact fp32),
// factored layer-1 (a, g). Blocks 0-1 also emit the W2 B-frag swizzle.
// ---------------------------------------------------------------------------
__global__ __launch_bounds__(256) void k0_pre(
    const float* __restrict__ pos, const float* __restrict__ feat,
    const float* __restrict__ W1, const float* __restrict__ b1,
    const float* __restrict__ W2,
    float* __restrict__ sq, float* __restrict__ a_out, float* __restrict__ g_out,
    unsigned short* __restrict__ poshi, unsigned short* __restrict__ w2sw) {
  __shared__ float fLds[4][64];
  const int lane = threadIdx.x & 63;
  const int rl = threadIdx.x >> 6;
  const int r = blockIdx.x * 4 + rl;

  float p = pos[r * 64 + lane];
  float f = feat[r * 64 + lane];
  fLds[rl][lane] = f;  // wave-private row; wave lockstep

  poshi[r * 64 + lane] = bf16rne(p);

  float s = p * p;
#pragma unroll
  for (int off = 1; off < 64; off <<= 1) s += __shfl_xor(s, off, 64);
  if (lane == 0) sq[r] = s;

  float acc_a = b1[lane];
  float acc_g = 0.f;
  const float4* f4 = reinterpret_cast<const float4*>(fLds[rl]);
#pragma unroll
  for (int i = 0; i < 16; ++i) {
    float4 fv = f4[i];
    float fd[4] = {fv.x, fv.y, fv.z, fv.w};
#pragma unroll
    for (int j = 0; j < 4; ++j) {
      int d = 4 * i + j;
      float wt = W1[d * 64 + lane];
      float wb = W1[(64 + d) * 64 + lane];
      acc_a = fmaf(fd[j], wt - wb, acc_a);
      acc_g = fmaf(fd[j], wb, acc_g);
    }
  }
  a_out[r * 64 + lane] = acc_a;
  g_out[r * 64 + lane] = acc_g;

  if (blockIdx.x < 2) {  // fused W2 swizzle (frag f = seg*4 + t)
    const int u = blockIdx.x * 256 + threadIdx.x;  // [0, 512)
    const int fr = u >> 6, ul = u & 63;
    const int seg = fr >> 2, t = fr & 3;
    const int uq = ul >> 4, uc = ul & 15;
#pragma unroll
    for (int j = 0; j < 8; ++j) {
      int d = seg * 32 + uq * 8 + j;
      w2sw[u * 8 + j] = bf16rne(W2[d * 64 + t * 16 + uc]);
    }
  }
}

// ---------------------------------------------------------------------------
// K1a: tau_q >= sample-20th d-hat (overestimate widens superset: safe).
// 256 blocks; top-8 per 128-cand stream; tau = 20th of 64 kept, +0.5 margin
// for hi-only d-hat error. A[m=lane&15][k=quad*8+j]; D: col=lane&15,
// row=quad*4+reg (m89-verified).
// ---------------------------------------------------------------------------
__global__ __launch_bounds__(256) void k1a_tau(
    const unsigned short* __restrict__ poshi,
    const float* __restrict__ sq, float* __restrict__ tau_g) {
  __shared__ float vw[4][16][36];        // wave-private transpose, 9 KiB
  __shared__ float sqcLds[SAMPLE];       // 4 KiB
  __shared__ float topLds[8][8][33];     // [stream][k][q], 8.25 KiB
  const int lane = threadIdx.x & 63;
  const int w = threadIdx.x >> 6;
  const int qbase = blockIdx.x * QT1A;
  const int col = lane & 15;
  const int quad = lane >> 4;
  const int dimOff = quad * 8;
  const int qq = lane & 31;     // query owned in cascade phase
  const int h = lane >> 5;      // candidate half owned

  for (int i = threadIdx.x; i < SAMPLE; i += 256) sqcLds[i] = sq[i];

  bf16x8 Ahi[2][2];
#pragma unroll
  for (int s = 0; s < 2; ++s) {
    int row = qbase + s * 16 + col;
    Ahi[s][0] = *(const bf16x8*)(poshi + (size_t)row * 64 + dimOff);
    Ahi[s][1] = *(const bf16x8*)(poshi + (size_t)row * 64 + dimOff + 32);
  }
  __syncthreads();  // sqcLds ready

  const f32x4 zf = {0.f, 0.f, 0.f, 0.f};
  float bd[8];
#pragma unroll
  for (int k = 0; k < 8; ++k) bd[k] = FLT_MAX;

  bf16x8 Bh0 = *(const bf16x8*)(poshi + (size_t)(w * 16 + col) * 64 + dimOff);
  bf16x8 Bh1 = *(const bf16x8*)(poshi + (size_t)(w * 16 + col) * 64 + dimOff + 32);
  for (int c0 = 0; c0 < SAMPLE; c0 += 64) {
    const int nc0 = (c0 + 64 < SAMPLE) ? c0 + 64 : c0;
    bf16x8 Nh0 = *(const bf16x8*)(poshi + (size_t)(nc0 + w * 16 + col) * 64 + dimOff);
    bf16x8 Nh1 = *(const bf16x8*)(poshi + (size_t)(nc0 + w * 16 + col) * 64 + dimOff + 32);

    f32x4 acc[2] = {zf, zf};
#pragma unroll
    for (int s = 0; s < 2; ++s) {
      acc[s] = __builtin_amdgcn_mfma_f32_16x16x32_bf16(Ahi[s][0], Bh0, acc[s], 0, 0, 0);
      acc[s] = __builtin_amdgcn_mfma_f32_16x16x32_bf16(Ahi[s][1], Bh1, acc[s], 0, 0, 0);
    }
    const float sqcv = sqcLds[c0 + w * 16 + col] + 256.0f;
#pragma unroll
    for (int s = 0; s < 2; ++s) {
      float4 v4;
      v4.x = fmaf(-2.f, acc[s][0], sqcv);
      v4.y = fmaf(-2.f, acc[s][1], sqcv);
      v4.z = fmaf(-2.f, acc[s][2], sqcv);
      v4.w = fmaf(-2.f, acc[s][3], sqcv);
      *reinterpret_cast<float4*>(&vw[w][col][s * 16 + quad * 4]) = v4;
    }
    __builtin_amdgcn_wave_barrier();  // wave-private region, lockstep
#pragma unroll
    for (int i = 0; i < 8; ++i) {
      float cd = vw[w][h * 8 + i][qq];
#pragma unroll
      for (int k = 0; k < 8; ++k) {  // branch-free sorted insert (top-8)
        float lo = fminf(cd, bd[k]);
        cd = fmaxf(cd, bd[k]);
        bd[k] = lo;
      }
    }
    __builtin_amdgcn_wave_barrier();
    Bh0 = Nh0; Bh1 = Nh1;
  }

#pragma unroll
  for (int k = 0; k < 8; ++k) topLds[w * 2 + h][k][qq] = bd[k];
  __syncthreads();

  if (threadIdx.x < QT1A) {
    const int l = threadIdx.x;
    int ix[8] = {0, 0, 0, 0, 0, 0, 0, 0};
    float tau = FLT_MAX;
    for (int k = 0; k < KNN; ++k) {
      float best = FLT_MAX;
      int bs = 0;
#pragma unroll
      for (int st = 0; st < 8; ++st) {
        float v = (ix[st] < 8) ? topLds[st][ix[st]][l] : FLT_MAX;
        if (v < best) { best = v; bs = st; }
      }
      ix[bs]++;
      tau = best;
    }
    tau_g[qbase + l] = tau + 0.5f;  // margin covers hi-only d-hat error
  }
}

// ---------------------------------------------------------------------------
// K1b v10: back to 256-thread blocks (v8 structure, VGPR ~84, no spills) but
// QT 128->64 so the grid doubles: 128x8 = 1024 blocks x 4 waves = 16 waves/CU
// = 4 waves/SIMD. Round-3 post-mortem: __launch_bounds__(512,4) squeezed
// VGPR 84->64 -> scratch spills -> +100 MB HBM traffic, dur 52->59. This
// version raises TLP via grid, SHRINKS per-wave state (4 A-groups not 8),
// and caps registers gently at 128 (launch_bounds(256,4)) so spilling is
// impossible. B-tile reuse halves (8 MFMA/load) but B reads are L2-resident.
// list/cnt layouts are per-query transposed -> downstream kernels untouched.
// ---------------------------------------------------------------------------
__global__ __launch_bounds__(256, 4) void k1b_collect(
    const unsigned short* __restrict__ poshi,
    const float* __restrict__ sq, const float* __restrict__ tau_g,
    unsigned* __restrict__ list, unsigned* __restrict__ cnt_ws) {
  __shared__ float sqcLds[CPB];      // 4 KiB
  __shared__ float tauLds[QT1B];
  __shared__ unsigned cntLds[QT1B];

  const int lane = threadIdx.x & 63;
  const int w = threadIdx.x >> 6;    // 0..3
  const int qbase = blockIdx.x * QT1B;
  const int cbase = blockIdx.y * CPB;
  const int col = lane & 15;
  const int quad = lane >> 4;
  const int dimOff = quad * 8;

  for (int i = threadIdx.x; i < CPB; i += 256) sqcLds[i] = sq[cbase + i];
  if (threadIdx.x < QT1B) {
    tauLds[threadIdx.x] = tau_g[qbase + threadIdx.x];
    cntLds[threadIdx.x] = 0;
  }

  // A-fragments: 4 groups of 16 queries (loaded once, reused for 16 stripes)
  bf16x8 Ahi[4][2];
#pragma unroll
  for (int s = 0; s < 4; ++s) {
    int row = qbase + s * 16 + col;
    Ahi[s][0] = *(const bf16x8*)(poshi + (size_t)row * 64 + dimOff);
    Ahi[s][1] = *(const bf16x8*)(poshi + (size_t)row * 64 + dimOff + 32);
  }
  __syncthreads();

  float tau_l[4][4];
#pragma unroll
  for (int s = 0; s < 4; ++s)
#pragma unroll
    for (int r = 0; r < 4; ++r) tau_l[s][r] = tauLds[s * 16 + quad * 4 + r];

  const f32x4 zf = {0.f, 0.f, 0.f, 0.f};
  bf16x8 Bh0 = *(const bf16x8*)(poshi + (size_t)(cbase + w * 16 + col) * 64 + dimOff);
  bf16x8 Bh1 = *(const bf16x8*)(poshi + (size_t)(cbase + w * 16 + col) * 64 + dimOff + 32);
  for (int c0 = 0; c0 < CPB; c0 += 64) {
    const int nc0 = (c0 + 64 < CPB) ? c0 + 64 : c0;
    bf16x8 Nh0 = *(const bf16x8*)(poshi + (size_t)(cbase + nc0 + w * 16 + col) * 64 + dimOff);
    bf16x8 Nh1 = *(const bf16x8*)(poshi + (size_t)(cbase + nc0 + w * 16 + col) * 64 + dimOff + 32);

    f32x4 acc[4] = {zf, zf, zf, zf};
#pragma unroll
    for (int s = 0; s < 4; ++s) {
      acc[s] = __builtin_amdgcn_mfma_f32_16x16x32_bf16(Ahi[s][0], Bh0, acc[s], 0, 0, 0);
      acc[s] = __builtin_amdgcn_mfma_f32_16x16x32_bf16(Ahi[s][1], Bh1, acc[s], 0, 0, 0);
    }
    const int candRow = cbase + c0 + w * 16 + col;
    const float sqcv = sqcLds[c0 + w * 16 + col] + 256.0f;
#pragma unroll
    for (int s = 0; s < 4; ++s) {
#pragma unroll
      for (int r = 0; r < 4; ++r) {
        float val = fmaf(-2.f, acc[s][r], sqcv);
        const int qrow = s * 16 + quad * 4 + r;  // D row = quad*4+reg
        if (val <= tau_l[s][r]) {  // ~2% of lanes
          unsigned slot = atomicAdd(&cntLds[qrow], 1u);
          if (slot < CAP)
            list[(size_t)(blockIdx.y * CAP + slot) * M_TOTAL + qbase + qrow] =
                (__float_as_uint(val) & 0xFFFFE000u) | (unsigned)candRow;
        }
      }
    }
    Bh0 = Nh0; Bh1 = Nh1;
  }
  __syncthreads();
  if (threadIdx.x < QT1B) {
    unsigned c = cntLds[threadIdx.x];
    cnt_ws[blockIdx.y * M_TOTAL + qbase + threadIdx.x] = c > CAP ? CAP : c;
  }
}

// ---------------------------------------------------------------------------
// K2ab: fused selection + MLP. 32 queries x 8 slices (1 partition each).
// Ph1: per-slice top-8 (coalesced; kept-20th >= true-20th, safe T).
// Ph2: 8-way merge -> 20th of kept -> guard T (+3 quanta for hi-only error).
// Ph3: rescan, collect quant <= T (~22/query).
// Ph4: 8 thr/query exact fp32 d2, sorted-5 each; merge top-20 -> nbrLds.
// Ph5 (fused former k2b): MLP via MFMA, 4 waves x 8 rounds over the block's
// 32 queries; nbr never leaves LDS; coalesced out store.
// ---------------------------------------------------------------------------
__global__ __launch_bounds__(256) void k2ab(
    const float* __restrict__ pos, const float* __restrict__ sq,
    const unsigned* __restrict__ list, const unsigned* __restrict__ cnt_ws,
    const float* __restrict__ a_in, const float* __restrict__ g_in,
    const unsigned short* __restrict__ w2sw, const float* __restrict__ b2,
    float* __restrict__ out) {
  __shared__ unsigned topLds[NSLICE][QT2][9];           // 9.2 KiB (pad 9)
  __shared__ unsigned TLds[QT2];
  __shared__ unsigned ccnt[QT2];
  __shared__ unsigned candLds[QT2][GCAP];               // 5.1 KiB
  __shared__ unsigned long long rrLds[NSLICE][QT2][6];  // 12.3 KiB (pad 6)
  __shared__ int nbrLds[QT2][KNN];                      // 2.5 KiB

  const int l = threadIdx.x & 31;   // query lane
  const int s = threadIdx.x >> 5;   // slice: partition s
  const int q = blockIdx.x * QT2 + l;

  // ---- phase 1: per-slice top-8 over collected keys (chunked loads) ----
  unsigned bd[8];
#pragma unroll
  for (int k = 0; k < 8; ++k) bd[k] = 0xFFFFFFFFu;
  {
    const unsigned c = cnt_ws[s * M_TOTAL + q];
    const unsigned* base = list + (size_t)(s * CAP) * M_TOTAL + q;
    for (unsigned sl0 = 0; sl0 < c; sl0 += 8) {
      unsigned kk[8];
#pragma unroll
      for (int j = 0; j < 8; ++j) {
        unsigned slj = sl0 + j;
        kk[j] = base[(size_t)(slj < c ? slj : 0) * M_TOTAL];  // 8 loads in flight
      }
#pragma unroll
      for (int j = 0; j < 8; ++j) {
        unsigned cd = (sl0 + j < c) ? kk[j] : 0xFFFFFFFFu;
#pragma unroll
        for (int k = 0; k < 8; ++k) {
          unsigned lo = cd < bd[k] ? cd : bd[k];
          cd = cd < bd[k] ? bd[k] : cd;
          bd[k] = lo;
        }
      }
    }
  }
#pragma unroll
  for (int k = 0; k < 8; ++k) topLds[s][l][k] = bd[k];
  __syncthreads();

  // ---- phase 2: 8-way merge -> 20th of kept -> guard T ----
  if (threadIdx.x < QT2) {
    int ix[8] = {0, 0, 0, 0, 0, 0, 0, 0};
    unsigned m = 0;
    for (int k = 0; k < KNN; ++k) {
      unsigned best = 0xFFFFFFFFu;
      int bs = 0;
#pragma unroll
      for (int st = 0; st < 8; ++st) {
        unsigned v = (ix[st] < 8) ? topLds[st][l][ix[st]] : 0xFFFFFFFFu;
        if (v < best) { best = v; bs = st; }
      }
      ix[bs]++;
      m = best;
    }
    TLds[l] = (m >> 13) + 3;
    ccnt[l] = 0;
  }
  __syncthreads();

  // ---- phase 3: rescan, collect guard set (chunked loads) ----
  const unsigned T = TLds[l];
  {
    const unsigned c = cnt_ws[s * M_TOTAL + q];
    const unsigned* base = list + (size_t)(s * CAP) * M_TOTAL + q;
    for (unsigned sl0 = 0; sl0 < c; sl0 += 8) {
      unsigned kk[8];
#pragma unroll
      for (int j = 0; j < 8; ++j) {
        unsigned slj = sl0 + j;
        kk[j] = base[(size_t)(slj < c ? slj : 0) * M_TOTAL];
      }
#pragma unroll
      for (int j = 0; j < 8; ++j) {
        if (sl0 + j < c && (kk[j] >> 13) <= T) {
          unsigned pos_ = atomicAdd(&ccnt[l], 1u);
          if (pos_ < GCAP) candLds[l][pos_] = kk[j] & 0x1FFFu;
        }
      }
    }
  }
  __syncthreads();

  // ---- phase 4: exact fp32 d2 re-rank of the guard set ----
  const int cc = min(ccnt[l], (unsigned)GCAP);
  const float sqq = sq[q];
  const float4* qp4 = reinterpret_cast<const float4*>(pos + (size_t)q * 64);
  unsigned long long kb[5];
#pragma unroll
  for (int j = 0; j < 5; ++j) kb[j] = ~0ull;
  for (int j = s; j < cc; j += NSLICE) {
    const unsigned idx = candLds[l][j];
    const float4* cp4 = reinterpret_cast<const float4*>(pos + (size_t)idx * 64);
    float d0 = 0.f, d1 = 0.f, d2 = 0.f, d3 = 0.f;
#pragma unroll
    for (int t = 0; t < 16; ++t) {
      float4 cv = cp4[t];
      float4 qv = qp4[t];  // L1/L2-hot
      d0 = fmaf(cv.x, qv.x, d0);
      d1 = fmaf(cv.y, qv.y, d1);
      d2 = fmaf(cv.z, qv.z, d2);
      d3 = fmaf(cv.w, qv.w, d3);
    }
    float dot = (d0 + d1) + (d2 + d3);
    float dd = fmaxf(fmaf(-2.f, dot, sqq + sq[idx]), 0.f);
    unsigned long long cd = ((unsigned long long)__float_as_uint(dd) << 32) | idx;
#pragma unroll
    for (int k = 0; k < 5; ++k) {  // sorted-5 insert (tie -> smaller idx)
      unsigned long long lo = cd < kb[k] ? cd : kb[k];
      cd = cd < kb[k] ? kb[k] : cd;
      kb[k] = lo;
    }
  }
#pragma unroll
  for (int j = 0; j < 5; ++j) rrLds[s][l][j] = kb[j];
  __syncthreads();

  if (threadIdx.x < QT2) {
    int ix[8] = {0, 0, 0, 0, 0, 0, 0, 0};
    for (int k = 0; k < KNN; ++k) {
      unsigned long long best = ~0ull;
      int bs = 0;
#pragma unroll
      for (int st = 0; st < 8; ++st) {
        unsigned long long v = (ix[st] < 5) ? rrLds[st][l][ix[st]] : ~0ull;
        if (v < best) { best = v; bs = st; }
      }
      ix[bs]++;
      nbrLds[l][k] = (int)(unsigned)(best & 0xFFFFFFFFu);
    }
  }
  __syncthreads();

  // ---- phase 5 (fused k2b): MLP + max-agg via MFMA, 4 waves x 8 rounds ----
  const int lane = threadIdx.x & 63;
  const int wv = threadIdx.x >> 6;
  const int col = lane & 15;
  const int quad = lane >> 4;

  bf16x8 Bf[8];
#pragma unroll
  for (int f = 0; f < 8; ++f)
    Bf[f] = *(const bf16x8*)(w2sw + ((size_t)f * 64 + lane) * 8);
  const float bias = b2[lane];

  for (int t = 0; t < 8; ++t) {
    const int li = t * 4 + wv;                 // local query 0..31
    const int q2 = blockIdx.x * QT2 + li;
    const int n0 = nbrLds[li][col];
    const int n1 = nbrLds[li][(16 + col) % KNN];

    const f32x4 zf = {0.f, 0.f, 0.f, 0.f};
    f32x4 acc0[4] = {zf, zf, zf, zf};
    f32x4 acc1[4] = {zf, zf, zf, zf};
#pragma unroll
    for (int seg = 0; seg < 2; ++seg) {
      const int dOff = seg * 32 + quad * 8;
      const float4* ap = reinterpret_cast<const float4*>(a_in + (size_t)q2 * 64 + dOff);
      const float4* g0p = reinterpret_cast<const float4*>(g_in + (size_t)n0 * 64 + dOff);
      const float4* g1p = reinterpret_cast<const float4*>(g_in + (size_t)n1 * 64 + dOff);
      float4 aa0 = ap[0], aa1 = ap[1];
      float4 gg0 = g0p[0], gg1 = g0p[1];
      float4 hh0 = g1p[0], hh1 = g1p[1];
      float av[8] = {aa0.x, aa0.y, aa0.z, aa0.w, aa1.x, aa1.y, aa1.z, aa1.w};
      float g0v[8] = {gg0.x, gg0.y, gg0.z, gg0.w, gg1.x, gg1.y, gg1.z, gg1.w};
      float g1v[8] = {hh0.x, hh0.y, hh0.z, hh0.w, hh1.x, hh1.y, hh1.z, hh1.w};
      bf16x8 A0, A1;
#pragma unroll
      for (int j = 0; j < 8; ++j) {
        A0[j] = (short)bf16rne(fmaxf(av[j] + g0v[j], 0.f));
        A1[j] = (short)bf16rne(fmaxf(av[j] + g1v[j], 0.f));
      }
#pragma unroll
      for (int tt = 0; tt < 4; ++tt) {
        acc0[tt] = __builtin_amdgcn_mfma_f32_16x16x32_bf16(A0, Bf[seg * 4 + tt], acc0[tt], 0, 0, 0);
        acc1[tt] = __builtin_amdgcn_mfma_f32_16x16x32_bf16(A1, Bf[seg * 4 + tt], acc1[tt], 0, 0, 0);
      }
    }
    float res = 0.f;
#pragma unroll
    for (int tt = 0; tt < 4; ++tt) {
      float m = fmaxf(fmaxf(fmaxf(acc0[tt][0], acc1[tt][0]), fmaxf(acc0[tt][1], acc1[tt][1])),
                      fmaxf(fmaxf(acc0[tt][2], acc1[tt][2]), fmaxf(acc0[tt][3], acc1[tt][3])));
      m = fmaxf(m, __shfl_xor(m, 16, 64));
      m = fmaxf(m, __shfl_xor(m, 32, 64));
      res = (quad == tt) ? m : res;  // o = tt*16+col == lane iff quad==tt
    }
    out[(size_t)q2 * 64 + lane] = res + bias;
  }
}

// ---------------------------------------------------------------------------
extern "C" void kernel_launch(void* const* d_in, const int* in_sizes, int n_in,
                              void* d_out, int out_size, void* d_ws, size_t ws_size,
                              hipStream_t stream) {
  const float* pos = (const float*)d_in[0];
  const float* feat = (const float*)d_in[1];
  const float* W1 = (const float*)d_in[2];
  const float* b1 = (const float*)d_in[3];
  const float* W2 = (const float*)d_in[4];
  const float* b2 = (const float*)d_in[5];
  float* out = (float*)d_out;

  // ws layout (bytes), total ~23.3 MiB:
  //   sq    @ 0         32 KiB
  //   a     @ 32768     2 MiB
  //   g     @ 2129920   2 MiB
  //   poshi @ 4227072   1 MiB
  //   w2sw  @ 6324224   8 KiB
  //   list  @ 6332416   16 MiB  (512 slots x 8192 queries, transposed u32 keys)
  //   cnt   @ 23109632  256 KiB (8 x 8192, transposed)
  //   tau   @ 23633920  32 KiB
  char* ws = (char*)d_ws;
  float* sq = (float*)ws;
  float* a = (float*)(ws + 32768);
  float* g = (float*)(ws + 2129920);
  unsigned short* poshi = (unsigned short*)(ws + 4227072);
  unsigned short* w2sw = (unsigned short*)(ws + 6324224);
  unsigned* list = (unsigned*)(ws + 6332416);
  unsigned* cnt_ws = (unsigned*)(ws + 23109632);
  float* tau_g = (float*)(ws + 23633920);

  k0_pre<<<M_TOTAL / 4, 256, 0, stream>>>(pos, feat, W1, b1, W2, sq, a, g, poshi, w2sw);
  k1a_tau<<<M_TOTAL / QT1A, 256, 0, stream>>>(poshi, sq, tau_g);
  k1b_collect<<<dim3(M_TOTAL / QT1B, PPART), 256, 0, stream>>>(poshi, sq, tau_g, list, cnt_ws);
  k2ab<<<M_TOTAL / QT2, 256, 0, stream>>>(pos, sq, list, cnt_ws, a, g, w2sw, b2, out);
}